// Round 1
// baseline (2293.779 us; speedup 1.0000x reference)
//
#include <hip/hip_runtime.h>
#include <math.h>

#define TDIM 32
#define BDIM 128
#define CDIM 512
#define HHDIM 256
#define NCDIM 6625
#define HWDIM 256

typedef __attribute__((ext_vector_type(8))) short sh8;
typedef __attribute__((ext_vector_type(4))) float f4;

__device__ inline short f2bf(float f) {
    union { float f; unsigned u; } v; v.f = f;
    unsigned u = v.u;
    unsigned r = u + 0x7fffu + ((u >> 16) & 1u);   // RNE
    return (short)(r >> 16);
}

__device__ inline sh8 frag8(const float* __restrict__ p) {
    f4 a = *(const f4*)p;
    f4 b = *(const f4*)(p + 4);
    sh8 r;
    r[0]=f2bf(a[0]); r[1]=f2bf(a[1]); r[2]=f2bf(a[2]); r[3]=f2bf(a[3]);
    r[4]=f2bf(b[0]); r[5]=f2bf(b[1]); r[6]=f2bf(b[2]); r[7]=f2bf(b[3]);
    return r;
}

__device__ inline float sigm(float x) { return 1.f / (1.f + expf(-x)); }

// ---------------------------------------------------------------------------
// att_norm: normalize attention_map over spatial dims, write to d_out att region
// grid: B*T blocks of 64 threads; each block handles one (b,t) row of 256
__global__ void att_norm(const float* __restrict__ att, float* __restrict__ outA) {
    int row = blockIdx.x;                 // b*T + t
    int tid = threadIdx.x;                // 0..63
    const float* p = att + (size_t)row * HWDIM;
    f4 v = *(const f4*)(p + tid * 4);
    float sum = v[0] + v[1] + v[2] + v[3];
    #pragma unroll
    for (int off = 32; off; off >>= 1) sum += __shfl_down(sum, off);
    float tot = __shfl(sum, 0);
    float inv = 1.f / tot;
    f4 o; o[0]=v[0]*inv; o[1]=v[1]*inv; o[2]=v[2]*inv; o[3]=v[3]*inv;
    *(f4*)(outA + (size_t)row * HWDIM + tid * 4) = o;
}

// ---------------------------------------------------------------------------
// Generic bf16 MFMA GEMM:  C[M,N] = A[M,K] @ W[N,K]^T (+ bias1[n] + bias2[n])
// wave computes 16Mx64N, block = 4 waves = 64Mx64N. gridDim.z = batch.
// MODE 0: out[m*N + n]
// MODE 1: out[((m%Bb)*Tt + m/Bb)*N + n]        (logits b*T+t remap)
// MODE 2: out[n*ocs + m + bz*obs]              (pooling scatter: cseq[t][b][c])
template<int MODE>
__global__ __launch_bounds__(256)
void gemm_bf16(const float* __restrict__ A, const float* __restrict__ W,
               const float* __restrict__ bias1, const float* __restrict__ bias2,
               float* __restrict__ out,
               int M, int N, int K,
               long a_bstride, long w_bstride, long obs, long ocs,
               int Bb, int Tt) {
    const int bz = blockIdx.z;
    A += (size_t)bz * a_bstride;
    W += (size_t)bz * w_bstride;
    const int wave = threadIdx.x >> 6;
    const int lane = threadIdx.x & 63;
    const int r = lane & 15, hh = lane >> 4;
    const int m0 = blockIdx.x * 64 + wave * 16;
    const int n0 = blockIdx.y * 64;

    f4 acc[4] = {};
    const float* arow = A + (size_t)(m0 + r) * K + hh * 8;
    const float* wrow[4];
    #pragma unroll
    for (int j = 0; j < 4; j++) {
        int nr = n0 + j * 16 + r;
        wrow[j] = W + (size_t)(nr < N ? nr : 0) * K + hh * 8;  // clamp; invalid cols never written
    }
    for (int kk = 0; kk < K; kk += 32) {
        sh8 af = frag8(arow + kk);
        #pragma unroll
        for (int j = 0; j < 4; j++) {
            sh8 bf = frag8(wrow[j] + kk);
            acc[j] = __builtin_amdgcn_mfma_f32_16x16x32_bf16(af, bf, acc[j], 0, 0, 0);
        }
    }
    #pragma unroll
    for (int j = 0; j < 4; j++) {
        int n = n0 + j * 16 + r;
        if (n >= N) continue;
        float bsum = (bias1 ? bias1[n] : 0.f) + (bias2 ? bias2[n] : 0.f);
        #pragma unroll
        for (int reg = 0; reg < 4; reg++) {
            int m = m0 + hh * 4 + reg;
            float vv = acc[j][reg] + bsum;
            size_t idx;
            if (MODE == 0)      idx = (size_t)m * N + n;
            else if (MODE == 1) idx = ((size_t)(m % Bb) * Tt + (m / Bb)) * N + n;
            else                idx = (size_t)n * ocs + m + (size_t)bz * obs;
            out[idx] = vv;
        }
    }
}

// ---------------------------------------------------------------------------
// emb_fill: xcat[t*B+b][512:1024] = char_embeddings[prev_idx[b][t]]
__global__ void emb_fill(const int* __restrict__ text, const float* __restrict__ emb,
                         float* __restrict__ xcat) {
    int n = blockIdx.x;                 // t*B + b
    int t = n >> 7;
    int b = n & 127;
    int idx = (t == 0) ? 0 : text[b * TDIM + (t - 1)];
    const f4* src = (const f4*)(emb + (size_t)idx * CDIM);
    f4* dst = (f4*)(xcat + (size_t)n * 1024 + 512);
    for (int j = threadIdx.x; j < CDIM / 4; j += 64) dst[j] = src[j];
}

// ---------------------------------------------------------------------------
// LSTM step (both directions). grid (16 u-tiles, 2 dirs), 256 threads (4 waves).
// gates[b][1024] = xgate[t][b][:] + h_prev[b][:] @ w_hh^T ; activation lane-local.
// h written into xcat columns [0:256) (fwd) / [256:512) (bwd).
__global__ __launch_bounds__(256)
void lstm_step(const float* __restrict__ xf, const float* __restrict__ xb,
               const float* __restrict__ whhf, const float* __restrict__ whhb,
               float* __restrict__ xcat, float* __restrict__ cstate, int s) {
    const int dir = blockIdx.y;
    const int t = dir ? (TDIM - 1 - s) : s;
    const float* xg = dir ? xb : xf;
    const float* whh = dir ? whhb : whhf;
    float* cst = cstate + (size_t)dir * BDIM * HHDIM;
    const int hprev_t = dir ? (t + 1) : (t - 1);
    const int dircol = dir ? HHDIM : 0;

    const int wave = threadIdx.x >> 6;
    const int lane = threadIdx.x & 63;
    const int r = lane & 15, hh = lane >> 4;
    const int u0 = blockIdx.x * 16;

    f4 acc[2][4] = {};
    if (s > 0) {
        const float* aBase = xcat + ((size_t)hprev_t * BDIM) * 1024 + dircol;
        const float* ar0 = aBase + (size_t)(wave * 32 + r) * 1024 + hh * 8;
        const float* ar1 = aBase + (size_t)(wave * 32 + 16 + r) * 1024 + hh * 8;
        const float* wr[4];
        #pragma unroll
        for (int g = 0; g < 4; g++)
            wr[g] = whh + (size_t)(g * HHDIM + u0 + r) * HHDIM + hh * 8;
        for (int kk = 0; kk < HHDIM; kk += 32) {
            sh8 a0 = frag8(ar0 + kk);
            sh8 a1 = frag8(ar1 + kk);
            #pragma unroll
            for (int g = 0; g < 4; g++) {
                sh8 bf = frag8(wr[g] + kk);
                acc[0][g] = __builtin_amdgcn_mfma_f32_16x16x32_bf16(a0, bf, acc[0][g], 0, 0, 0);
                acc[1][g] = __builtin_amdgcn_mfma_f32_16x16x32_bf16(a1, bf, acc[1][g], 0, 0, 0);
            }
        }
    }
    const int u = u0 + r;
    #pragma unroll
    for (int mt = 0; mt < 2; mt++) {
        #pragma unroll
        for (int reg = 0; reg < 4; reg++) {
            int m = wave * 32 + mt * 16 + hh * 4 + reg;
            const float* xrow = xg + ((size_t)t * BDIM + m) * 1024;
            float gI = acc[mt][0][reg] + xrow[u];
            float gF = acc[mt][1][reg] + xrow[256 + u];
            float gG = acc[mt][2][reg] + xrow[512 + u];
            float gO = acc[mt][3][reg] + xrow[768 + u];
            float cold = (s == 0) ? 0.f : cst[m * HHDIM + u];
            float cnew = sigm(gF) * cold + sigm(gI) * tanhf(gG);
            float h = sigm(gO) * tanhf(cnew);
            cst[m * HHDIM + u] = cnew;
            xcat[((size_t)t * BDIM + m) * 1024 + dircol + u] = h;
        }
    }
}

// ---------------------------------------------------------------------------
// GRU step. grid (32 u-tiles), 256 threads. gh = h_prev @ w_hh^T (+b_hh),
// gi precomputed (incl b_ih). gates r,z,n lane-local. h -> gres[t][b][c].
__global__ __launch_bounds__(256)
void gru_step(const float* __restrict__ gi, const float* __restrict__ whh,
              const float* __restrict__ bhh, float* __restrict__ gres, int s) {
    const int t = s;
    const int wave = threadIdx.x >> 6;
    const int lane = threadIdx.x & 63;
    const int r = lane & 15, hh = lane >> 4;
    const int u0 = blockIdx.x * 16;

    f4 acc[2][3] = {};
    if (s > 0) {
        const float* aBase = gres + ((size_t)(t - 1) * BDIM) * CDIM;
        const float* ar0 = aBase + (size_t)(wave * 32 + r) * CDIM + hh * 8;
        const float* ar1 = aBase + (size_t)(wave * 32 + 16 + r) * CDIM + hh * 8;
        const float* wr[3];
        #pragma unroll
        for (int g = 0; g < 3; g++)
            wr[g] = whh + (size_t)(g * CDIM + u0 + r) * CDIM + hh * 8;
        for (int kk = 0; kk < CDIM; kk += 32) {
            sh8 a0 = frag8(ar0 + kk);
            sh8 a1 = frag8(ar1 + kk);
            #pragma unroll
            for (int g = 0; g < 3; g++) {
                sh8 bf = frag8(wr[g] + kk);
                acc[0][g] = __builtin_amdgcn_mfma_f32_16x16x32_bf16(a0, bf, acc[0][g], 0, 0, 0);
                acc[1][g] = __builtin_amdgcn_mfma_f32_16x16x32_bf16(a1, bf, acc[1][g], 0, 0, 0);
            }
        }
    }
    const int u = u0 + r;
    #pragma unroll
    for (int mt = 0; mt < 2; mt++) {
        #pragma unroll
        for (int reg = 0; reg < 4; reg++) {
            int m = wave * 32 + mt * 16 + hh * 4 + reg;
            const float* girow = gi + ((size_t)t * BDIM + m) * 1536;
            float ghr = acc[mt][0][reg] + bhh[u];
            float ghz = acc[mt][1][reg] + bhh[512 + u];
            float ghn = acc[mt][2][reg] + bhh[1024 + u];
            float rr = sigm(girow[u] + ghr);
            float zz = sigm(girow[512 + u] + ghz);
            float nn = tanhf(girow[1024 + u] + rr * ghn);
            float hp = (s == 0) ? 0.f : gres[((size_t)(t - 1) * BDIM + m) * CDIM + u];
            float h = (1.f - zz) * nn + zz * hp;
            gres[((size_t)t * BDIM + m) * CDIM + u] = h;
        }
    }
}

// ---------------------------------------------------------------------------
extern "C" void kernel_launch(void* const* d_in, const int* in_sizes, int n_in,
                              void* d_out, int out_size, void* d_ws, size_t ws_size,
                              hipStream_t stream) {
    const float* feature = (const float*)d_in[0];
    const float* attmap  = (const float*)d_in[1];
    const int*   text    = (const int*)d_in[2];
    const float* cemb    = (const float*)d_in[4];
    const float* wihf    = (const float*)d_in[5];
    const float* whhf    = (const float*)d_in[6];
    const float* bihf    = (const float*)d_in[7];
    const float* bhhf    = (const float*)d_in[8];
    const float* wihb    = (const float*)d_in[9];
    const float* whhb    = (const float*)d_in[10];
    const float* bihb    = (const float*)d_in[11];
    const float* bhhb    = (const float*)d_in[12];
    const float* gwih    = (const float*)d_in[13];
    const float* gwhh    = (const float*)d_in[14];
    const float* gbih    = (const float*)d_in[15];
    const float* gbhh    = (const float*)d_in[16];
    const float* genw    = (const float*)d_in[17];
    const float* genb    = (const float*)d_in[18];

    float* out    = (float*)d_out;
    float* outAtt = out + (size_t)4096 * NCDIM;   // [B*T, H, W] region

    float* ws   = (float*)d_ws;
    float* cseq = ws;                               // [T,B,C]      4096*512
    float* xf   = cseq + (size_t)4096 * 512;        // [T,B,1024]
    float* xb   = xf   + (size_t)4096 * 1024;
    float* xcat = xb   + (size_t)4096 * 1024;       // [T,B,1024]  (h_f|h_b|emb)
    float* gi   = xcat + (size_t)4096 * 1024;       // [T,B,1536]
    float* gres = gi   + (size_t)4096 * 1536;       // [T,B,512]
    float* cst  = gres + (size_t)4096 * 512;        // [2,128,256]

    // 1. normalize attention -> d_out att region (fp32, exact)
    att_norm<<<dim3(4096), dim3(64), 0, stream>>>(attmap, outAtt);

    // 2. pooling: per-b GEMM [512x256]x[256x32] -> cseq[t][b][c]
    gemm_bf16<2><<<dim3(8, 1, 128), dim3(256), 0, stream>>>(
        feature, outAtt, nullptr, nullptr, cseq,
        512, 32, 256, (long)512 * 256, (long)32 * 256, 512, (long)BDIM * 512, BDIM, TDIM);

    // 3. LSTM input gates: xf/xb = cseq @ w_ih^T + (b_ih + b_hh)
    gemm_bf16<0><<<dim3(64, 16, 1), dim3(256), 0, stream>>>(
        cseq, wihf, bihf, bhhf, xf, 4096, 1024, 512, 0, 0, 0, 0, BDIM, TDIM);
    gemm_bf16<0><<<dim3(64, 16, 1), dim3(256), 0, stream>>>(
        cseq, wihb, bihb, bhhb, xb, 4096, 1024, 512, 0, 0, 0, 0, BDIM, TDIM);

    // 4. previous-char embeddings into xcat[:,512:1024]
    emb_fill<<<dim3(4096), dim3(64), 0, stream>>>(text, cemb, xcat);

    // 5. 32 BiLSTM steps (fwd+bwd fused per launch); h into xcat[:,0:512)
    for (int s = 0; s < TDIM; s++)
        lstm_step<<<dim3(16, 2), dim3(256), 0, stream>>>(xf, xb, whhf, whhb, xcat, cst, s);

    // 6. GRU input gates: gi = xcat @ gru_w_ih^T + gru_b_ih
    gemm_bf16<0><<<dim3(64, 24, 1), dim3(256), 0, stream>>>(
        xcat, gwih, gbih, nullptr, gi, 4096, 1536, 1024, 0, 0, 0, 0, BDIM, TDIM);

    // 7. 32 GRU steps -> gres[t][b][c]
    for (int s = 0; s < TDIM; s++)
        gru_step<<<dim3(32, 1), dim3(256), 0, stream>>>(gi, gwhh, gbhh, gres, s);

    // 8. logits = gres @ gen_w^T + gen_b, remapped to out[(b*T+t)*NC + n]
    gemm_bf16<1><<<dim3(64, 104, 1), dim3(256), 0, stream>>>(
        gres, genw, genb, nullptr, out, 4096, NCDIM, 512, 0, 0, 0, 0, BDIM, TDIM);
}

// Round 2
// 1042.881 us; speedup vs baseline: 2.1995x; 2.1995x over previous
//
#include <hip/hip_runtime.h>
#include <math.h>

typedef __attribute__((ext_vector_type(8))) short sh8;
typedef __attribute__((ext_vector_type(4))) short sh4;
typedef __attribute__((ext_vector_type(4))) float f4;

__device__ inline short f2bf(float f) {
    union { float f; unsigned u; } v; v.f = f;
    unsigned u = v.u;
    return (short)((u + 0x7fffu + ((u >> 16) & 1u)) >> 16);   // RNE
}
__device__ inline float bf2f(short x) {
    union { unsigned u; float f; } v; v.u = ((unsigned)(unsigned short)x) << 16; return v.f;
}
__device__ inline float sigm(float x) { return 1.f / (1.f + expf(-x)); }

__device__ inline sh8 frag8(const float* __restrict__ p) {
    f4 a = *(const f4*)p;
    f4 b = *(const f4*)(p + 4);
    sh8 r;
    r[0]=f2bf(a[0]); r[1]=f2bf(a[1]); r[2]=f2bf(a[2]); r[3]=f2bf(a[3]);
    r[4]=f2bf(b[0]); r[5]=f2bf(b[1]); r[6]=f2bf(b[2]); r[7]=f2bf(b[3]);
    return r;
}

// ---------------------------------------------------------------------------
// cvt_bf16: batch fp32 -> bf16 weight conversion (7 jobs in one launch)
struct CvtPack { const float* s[7]; short* d[7]; int n4[7]; };
__global__ void cvt_bf16(CvtPack p) {
    int job = blockIdx.y;
    const f4* s = (const f4*)p.s[job];
    sh4* d = (sh4*)p.d[job];
    int n4 = p.n4[job];
    for (int i = blockIdx.x * blockDim.x + threadIdx.x; i < n4; i += gridDim.x * blockDim.x) {
        f4 v = s[i];
        sh4 o; o[0]=f2bf(v[0]); o[1]=f2bf(v[1]); o[2]=f2bf(v[2]); o[3]=f2bf(v[3]);
        d[i] = o;
    }
}

// ---------------------------------------------------------------------------
// att_norm: normalize attention over spatial dims -> d_out att region (fp32)
__global__ void att_norm(const float* __restrict__ att, float* __restrict__ outA) {
    int row = blockIdx.x;                 // b*T + t
    int tid = threadIdx.x;                // 0..63
    const float* p = att + (size_t)row * 256;
    f4 v = *(const f4*)(p + tid * 4);
    float sum = v[0] + v[1] + v[2] + v[3];
    #pragma unroll
    for (int off = 32; off; off >>= 1) sum += __shfl_down(sum, off);
    float inv = 1.f / __shfl(sum, 0);
    f4 o; o[0]=v[0]*inv; o[1]=v[1]*inv; o[2]=v[2]*inv; o[3]=v[3]*inv;
    *(f4*)(outA + (size_t)row * 256 + tid * 4) = o;
}

// ---------------------------------------------------------------------------
// pool_gemm: per-batch cseq[t][b][c] = sum_hw feature[b][c][hw] * att[b][t][hw]
// grid (8 c-tiles, 128 batches), 256 threads. Output bf16.
__global__ __launch_bounds__(256)
void pool_gemm(const float* __restrict__ feature, const float* __restrict__ att,
               short* __restrict__ cseqb) {
    int bz = blockIdx.y;
    const float* A  = feature + (size_t)bz * 512 * 256;
    const float* Wt = att + (size_t)bz * 32 * 256;
    int wave = threadIdx.x >> 6, lane = threadIdx.x & 63, r = lane & 15, hh = lane >> 4;
    int m0 = blockIdx.x * 64 + wave * 16;
    f4 acc[2] = {};
    const float* ar = A  + (size_t)(m0 + r) * 256 + hh * 8;
    const float* w0 = Wt + (size_t)r * 256 + hh * 8;
    const float* w1 = Wt + (size_t)(16 + r) * 256 + hh * 8;
    for (int kk = 0; kk < 256; kk += 32) {
        sh8 af = frag8(ar + kk);
        acc[0] = __builtin_amdgcn_mfma_f32_16x16x32_bf16(af, frag8(w0 + kk), acc[0], 0, 0, 0);
        acc[1] = __builtin_amdgcn_mfma_f32_16x16x32_bf16(af, frag8(w1 + kk), acc[1], 0, 0, 0);
    }
    #pragma unroll
    for (int j = 0; j < 2; j++) {
        int t = j * 16 + r;
        #pragma unroll
        for (int reg = 0; reg < 4; reg++) {
            int c = m0 + hh * 4 + reg;
            cseqb[(size_t)t * 65536 + (size_t)bz * 512 + c] = f2bf(acc[j][reg]);
        }
    }
}

// ---------------------------------------------------------------------------
// gemm128: C[M,N] = A[M,K] @ W[N,K]^T + bias. bf16 operands, fp32 out.
// 128x128 tile, BK=32, double-buffered LDS via global_load_lds (16B), 4 waves.
// MODE 0: out[m*N+n]   MODE 1: out[((m&127)*32 + (m>>7))*N + n]  (logits remap)
template<int MODE>
__global__ __launch_bounds__(256)
void gemm128(const short* __restrict__ A, const short* __restrict__ W,
             const float* __restrict__ bias1, const float* __restrict__ bias2,
             float* __restrict__ out, int M, int N, int K) {
    __shared__ short lds[2][2][4096];   // [buf][A/W][128*32]
    const int tid = threadIdx.x, wave = tid >> 6, lane = tid & 63;
    const int r = lane & 15, hh = lane >> 4;
    const int wm = wave >> 1, wn = wave & 1;
    const int m0 = blockIdx.x * 128, n0 = blockIdx.y * 128;

    // staging: 512 16B-chunks per 8KB tile; thread handles chunks tid and 256+tid
    const int c0 = tid, c1 = 256 + tid;
    const short* gA0 = A + (size_t)(m0 + (c0 >> 2)) * K + (c0 & 3) * 8;
    const short* gA1 = A + (size_t)(m0 + (c1 >> 2)) * K + (c1 & 3) * 8;
    int wr0 = n0 + (c0 >> 2); if (wr0 > N - 1) wr0 = N - 1;
    int wr1 = n0 + (c1 >> 2); if (wr1 > N - 1) wr1 = N - 1;
    const short* gW0 = W + (size_t)wr0 * K + (c0 & 3) * 8;
    const short* gW1 = W + (size_t)wr1 * K + (c1 & 3) * 8;
    const int lo0 = (wave * 64) * 8, lo1 = (256 + wave * 64) * 8;  // wave-uniform LDS elem bases

    auto stage = [&](int buf, int kt) {
        int ko = kt * 32;
        __builtin_amdgcn_global_load_lds((const __attribute__((address_space(1))) void*)(gA0 + ko),
            (__attribute__((address_space(3))) void*)&lds[buf][0][lo0], 16, 0, 0);
        __builtin_amdgcn_global_load_lds((const __attribute__((address_space(1))) void*)(gA1 + ko),
            (__attribute__((address_space(3))) void*)&lds[buf][0][lo1], 16, 0, 0);
        __builtin_amdgcn_global_load_lds((const __attribute__((address_space(1))) void*)(gW0 + ko),
            (__attribute__((address_space(3))) void*)&lds[buf][1][lo0], 16, 0, 0);
        __builtin_amdgcn_global_load_lds((const __attribute__((address_space(1))) void*)(gW1 + ko),
            (__attribute__((address_space(3))) void*)&lds[buf][1][lo1], 16, 0, 0);
    };

    f4 acc[4][4] = {};
    const int NT = K / 32;
    int cur = 0;

    stage(0, 0);
    __syncthreads();
    for (int kt = 0; kt < NT; ++kt) {
        if (kt + 1 < NT) stage(cur ^ 1, kt + 1);
        const short* As = &lds[cur][0][0];
        const short* Ws = &lds[cur][1][0];
        sh8 a[4], b[4];
        #pragma unroll
        for (int i = 0; i < 4; i++) a[i] = *(const sh8*)(As + (wm * 64 + i * 16 + r) * 32 + hh * 8);
        #pragma unroll
        for (int i = 0; i < 4; i++) b[i] = *(const sh8*)(Ws + (wn * 64 + i * 16 + r) * 32 + hh * 8);
        #pragma unroll
        for (int i = 0; i < 4; i++)
            #pragma unroll
            for (int j = 0; j < 4; j++)
                acc[i][j] = __builtin_amdgcn_mfma_f32_16x16x32_bf16(a[i], b[j], acc[i][j], 0, 0, 0);
        __syncthreads();
        cur ^= 1;
    }

    #pragma unroll
    for (int j = 0; j < 4; j++) {
        int n = n0 + wn * 64 + j * 16 + r;
        if (n >= N) continue;
        float bs = (bias1 ? bias1[n] : 0.f) + (bias2 ? bias2[n] : 0.f);
        #pragma unroll
        for (int i = 0; i < 4; i++) {
            #pragma unroll
            for (int reg = 0; reg < 4; reg++) {
                int m = m0 + wm * 64 + i * 16 + hh * 4 + reg;
                size_t idx;
                if (MODE == 0) idx = (size_t)m * N + n;
                else           idx = ((size_t)(m & 127) * 32 + (m >> 7)) * (size_t)N + n;
                out[idx] = acc[i][j][reg] + bs;
            }
        }
    }
}

// ---------------------------------------------------------------------------
// emb_fill: xcatb[t*B+b][512:1024] = bf16(char_embeddings[prev_idx[b][t]])
__global__ void emb_fill(const int* __restrict__ text, const float* __restrict__ emb,
                         short* __restrict__ xcatb) {
    int n = blockIdx.x;                 // t*B + b
    int t = n >> 7, b = n & 127;
    int idx = (t == 0) ? 0 : text[b * 32 + (t - 1)];
    const f4* src = (const f4*)(emb + (size_t)idx * 512);
    sh4* dst = (sh4*)(xcatb + (size_t)n * 1024 + 512);
    for (int j = threadIdx.x; j < 128; j += 64) {
        f4 v = src[j];
        sh4 o; o[0]=f2bf(v[0]); o[1]=f2bf(v[1]); o[2]=f2bf(v[2]); o[3]=f2bf(v[3]);
        dst[j] = o;
    }
}

// ---------------------------------------------------------------------------
// lstm_step2: bf16 weights + bf16 h state. grid (16 u-tiles, 2 dirs), 256 thr.
__global__ __launch_bounds__(256)
void lstm_step2(const float* __restrict__ xf, const float* __restrict__ xb,
                const short* __restrict__ whhf_b, const short* __restrict__ whhb_b,
                short* __restrict__ xcatb, float* __restrict__ cst, int s) {
    const int dir = blockIdx.y;
    const int t = dir ? (31 - s) : s;
    const float* xg = dir ? xb : xf;
    const short* whh = dir ? whhb_b : whhf_b;
    float* cs = cst + (size_t)dir * 128 * 256;
    const int hpt = dir ? (t + 1) : (t - 1);
    const int dcol = dir ? 256 : 0;

    const int wave = threadIdx.x >> 6, lane = threadIdx.x & 63;
    const int r = lane & 15, hh = lane >> 4;
    const int u0 = blockIdx.x * 16;

    f4 acc[2][4] = {};
    if (s > 0) {
        const short* a0p = xcatb + ((size_t)hpt * 128 + wave * 32 + r) * 1024 + dcol + hh * 8;
        const short* a1p = a0p + (size_t)16 * 1024;
        const short* wp[4];
        #pragma unroll
        for (int g = 0; g < 4; g++)
            wp[g] = whh + (size_t)(g * 256 + u0 + r) * 256 + hh * 8;
        for (int kk = 0; kk < 256; kk += 32) {
            sh8 a0 = *(const sh8*)(a0p + kk);
            sh8 a1 = *(const sh8*)(a1p + kk);
            #pragma unroll
            for (int g = 0; g < 4; g++) {
                sh8 bf = *(const sh8*)(wp[g] + kk);
                acc[0][g] = __builtin_amdgcn_mfma_f32_16x16x32_bf16(a0, bf, acc[0][g], 0, 0, 0);
                acc[1][g] = __builtin_amdgcn_mfma_f32_16x16x32_bf16(a1, bf, acc[1][g], 0, 0, 0);
            }
        }
    }
    const int u = u0 + r;
    #pragma unroll
    for (int mt = 0; mt < 2; mt++) {
        #pragma unroll
        for (int reg = 0; reg < 4; reg++) {
            int m = wave * 32 + mt * 16 + hh * 4 + reg;
            const float* xr = xg + ((size_t)t * 128 + m) * 1024;
            float gI = acc[mt][0][reg] + xr[u];
            float gF = acc[mt][1][reg] + xr[256 + u];
            float gG = acc[mt][2][reg] + xr[512 + u];
            float gO = acc[mt][3][reg] + xr[768 + u];
            float cold = (s == 0) ? 0.f : cs[m * 256 + u];
            float cn = sigm(gF) * cold + sigm(gI) * tanhf(gG);
            float h = sigm(gO) * tanhf(cn);
            cs[m * 256 + u] = cn;
            xcatb[((size_t)t * 128 + m) * 1024 + dcol + u] = f2bf(h);
        }
    }
}

// ---------------------------------------------------------------------------
// gru_step2: bf16 weights + bf16 h state. grid (32 u-tiles), 256 threads.
__global__ __launch_bounds__(256)
void gru_step2(const float* __restrict__ gi, const short* __restrict__ whh,
               const float* __restrict__ bhh, short* __restrict__ gresb, int s) {
    const int t = s;
    const int wave = threadIdx.x >> 6, lane = threadIdx.x & 63;
    const int r = lane & 15, hh = lane >> 4;
    const int u0 = blockIdx.x * 16;

    f4 acc[2][3] = {};
    if (s > 0) {
        const short* a0p = gresb + ((size_t)(t - 1) * 128 + wave * 32 + r) * 512 + hh * 8;
        const short* a1p = a0p + (size_t)16 * 512;
        const short* wp[3];
        #pragma unroll
        for (int g = 0; g < 3; g++)
            wp[g] = whh + (size_t)(g * 512 + u0 + r) * 512 + hh * 8;
        for (int kk = 0; kk < 512; kk += 32) {
            sh8 a0 = *(const sh8*)(a0p + kk);
            sh8 a1 = *(const sh8*)(a1p + kk);
            #pragma unroll
            for (int g = 0; g < 3; g++) {
                sh8 bf = *(const sh8*)(wp[g] + kk);
                acc[0][g] = __builtin_amdgcn_mfma_f32_16x16x32_bf16(a0, bf, acc[0][g], 0, 0, 0);
                acc[1][g] = __builtin_amdgcn_mfma_f32_16x16x32_bf16(a1, bf, acc[1][g], 0, 0, 0);
            }
        }
    }
    const int u = u0 + r;
    #pragma unroll
    for (int mt = 0; mt < 2; mt++) {
        #pragma unroll
        for (int reg = 0; reg < 4; reg++) {
            int m = wave * 32 + mt * 16 + hh * 4 + reg;
            const float* gir = gi + ((size_t)t * 128 + m) * 1536;
            float ghr = acc[mt][0][reg] + bhh[u];
            float ghz = acc[mt][1][reg] + bhh[512 + u];
            float ghn = acc[mt][2][reg] + bhh[1024 + u];
            float rr = sigm(gir[u] + ghr);
            float zz = sigm(gir[512 + u] + ghz);
            float nn = tanhf(gir[1024 + u] + rr * ghn);
            float hp = (s == 0) ? 0.f : bf2f(gresb[((size_t)(t - 1) * 128 + m) * 512 + u]);
            float h = (1.f - zz) * nn + zz * hp;
            gresb[((size_t)t * 128 + m) * 512 + u] = f2bf(h);
        }
    }
}

// ---------------------------------------------------------------------------
extern "C" void kernel_launch(void* const* d_in, const int* in_sizes, int n_in,
                              void* d_out, int out_size, void* d_ws, size_t ws_size,
                              hipStream_t stream) {
    const float* feature = (const float*)d_in[0];
    const float* attmap  = (const float*)d_in[1];
    const int*   text    = (const int*)d_in[2];
    const float* cemb    = (const float*)d_in[4];
    const float* wihf    = (const float*)d_in[5];
    const float* whhf    = (const float*)d_in[6];
    const float* bihf    = (const float*)d_in[7];
    const float* bhhf    = (const float*)d_in[8];
    const float* wihb    = (const float*)d_in[9];
    const float* whhb    = (const float*)d_in[10];
    const float* bihb    = (const float*)d_in[11];
    const float* bhhb    = (const float*)d_in[12];
    const float* gwih    = (const float*)d_in[13];
    const float* gwhh    = (const float*)d_in[14];
    const float* gbih    = (const float*)d_in[15];
    const float* gbhh    = (const float*)d_in[16];
    const float* genw    = (const float*)d_in[17];
    const float* genb    = (const float*)d_in[18];

    float* out    = (float*)d_out;
    float* outAtt = out + (size_t)4096 * 6625;

    // workspace layout
    float* xf  = (float*)d_ws;                 // [32*128][1024]
    float* xb  = xf + 4194304;
    float* gi  = xb + 4194304;                 // [32*128][1536]
    float* cst = gi + 6291456;                 // [2][128][256]
    short* cseqb  = (short*)(cst + 65536);     // [32*128][512]  (cseq[t][b][c])
    short* xcatb  = cseqb + 2097152;           // [32*128][1024] (h_f|h_b|emb)
    short* gresb  = xcatb + 4194304;           // [32*128][512]
    short* wihf_b = gresb + 2097152;
    short* wihb_b = wihf_b + 524288;
    short* whhf_b = wihb_b + 524288;
    short* whhb_b = whhf_b + 262144;
    short* gwih_b = whhb_b + 262144;
    short* gwhh_b = gwih_b + 1572864;
    short* genw_b = gwhh_b + 786432;

    // 0. weight conversion fp32 -> bf16 (7 jobs)
    CvtPack p;
    p.s[0] = wihf; p.d[0] = wihf_b; p.n4[0] = 524288 / 4;
    p.s[1] = wihb; p.d[1] = wihb_b; p.n4[1] = 524288 / 4;
    p.s[2] = whhf; p.d[2] = whhf_b; p.n4[2] = 262144 / 4;
    p.s[3] = whhb; p.d[3] = whhb_b; p.n4[3] = 262144 / 4;
    p.s[4] = gwih; p.d[4] = gwih_b; p.n4[4] = 1572864 / 4;
    p.s[5] = gwhh; p.d[5] = gwhh_b; p.n4[5] = 786432 / 4;
    p.s[6] = genw; p.d[6] = genw_b; p.n4[6] = 3392000 / 4;
    cvt_bf16<<<dim3(512, 7), dim3(256), 0, stream>>>(p);

    // 1. normalize attention -> d_out att region (fp32, exact)
    att_norm<<<dim3(4096), dim3(64), 0, stream>>>(attmap, outAtt);

    // 2. attention pooling -> cseqb (bf16)
    pool_gemm<<<dim3(8, 128), dim3(256), 0, stream>>>(feature, outAtt, cseqb);

    // 3. LSTM input gates: xf/xb = cseq @ w_ih^T + (b_ih + b_hh)
    gemm128<0><<<dim3(32, 8), dim3(256), 0, stream>>>(cseqb, wihf_b, bihf, bhhf, xf, 4096, 1024, 512);
    gemm128<0><<<dim3(32, 8), dim3(256), 0, stream>>>(cseqb, wihb_b, bihb, bhhb, xb, 4096, 1024, 512);

    // 4. previous-char embeddings into xcatb[:,512:1024]
    emb_fill<<<dim3(4096), dim3(64), 0, stream>>>(text, cemb, xcatb);

    // 5. 32 BiLSTM steps; h (bf16) into xcatb[:,0:512)
    for (int s = 0; s < 32; s++)
        lstm_step2<<<dim3(16, 2), dim3(256), 0, stream>>>(xf, xb, whhf_b, whhb_b, xcatb, cst, s);

    // 6. GRU input gates: gi = xcat @ gru_w_ih^T + gru_b_ih
    gemm128<0><<<dim3(32, 12), dim3(256), 0, stream>>>(xcatb, gwih_b, gbih, nullptr, gi, 4096, 1536, 1024);

    // 7. 32 GRU steps -> gresb (bf16)
    for (int s = 0; s < 32; s++)
        gru_step2<<<dim3(32, 1), dim3(256), 0, stream>>>(gi, gwhh_b, gbhh, gresb, s);

    // 8. logits = gres @ gen_w^T + gen_b, remapped to out[(b*T+t)*NC + n]
    gemm128<1><<<dim3(32, 52), dim3(256), 0, stream>>>(gresb, genw_b, genb, nullptr, out, 4096, 6625, 512);
}